// Round 1
// baseline (133.534 us; speedup 1.0000x reference)
//
#include <hip/hip_runtime.h>
#include <cstdint>

// ChamferLoss on MI355X.
// Work decomposition:
//   nn_kernel (x2, roles swapped): for each query point, min squared distance +
//     argmin over a target chunk staged in LDS; partials merged across chunks
//     via atomicMin on packed (d2_bits<<32 | n) u64 keys in workspace.
//   combine_kernel (x2): unpack key, sqrt, gather partner sigma, log+div,
//     block-reduce, scaled atomicAdd into d_out (memset to 0 each launch).

#define BLK 256
#define TM 4
#define MTILE (BLK * TM)   // 1024 query points per block
#define NCHUNK 512         // target points staged in LDS per block

__global__ __launch_bounds__(BLK) void nn_kernel(
    const float* __restrict__ Q, const float* __restrict__ T,
    unsigned long long* __restrict__ keys, int Mq, int Nt)
{
    const int nChunks = Nt / NCHUNK;
    const int mTiles  = Mq / MTILE;
    int bid = blockIdx.x;
    int nc = bid % nChunks;
    int mt = (bid / nChunks) % mTiles;
    int b  = bid / (nChunks * mTiles);

    __shared__ float4 sT[NCHUNK];

    const float* Tb = T + (size_t)b * 3 * Nt;
    const int n0 = nc * NCHUNK;
    // Stage target chunk: x,y,z and squared norm. Coalesced global reads.
    for (int i = threadIdx.x; i < NCHUNK; i += BLK) {
        float x = Tb[0 * Nt + n0 + i];
        float y = Tb[1 * Nt + n0 + i];
        float z = Tb[2 * Nt + n0 + i];
        sT[i] = make_float4(x, y, z, fmaf(x, x, fmaf(y, y, z * z)));
    }
    __syncthreads();

    const float* Qb = Q + (size_t)b * 3 * Mq;
    const int mBase = mt * MTILE;

    float x1[TM], y1[TM], z1[TM], sq1[TM], best[TM];
    int bi[TM];
#pragma unroll
    for (int i = 0; i < TM; ++i) {
        int m = mBase + (int)threadIdx.x + i * BLK;   // coalesced
        x1[i] = Qb[0 * Mq + m];
        y1[i] = Qb[1 * Mq + m];
        z1[i] = Qb[2 * Mq + m];
        sq1[i] = fmaf(x1[i], x1[i], fmaf(y1[i], y1[i], z1[i] * z1[i]));
        best[i] = 3.402823466e38f;
        bi[i] = 0;
    }

    // Inner loop: LDS broadcast read (all lanes same addr -> conflict-free),
    // ~8 VALU per pair. d2 = sq1 + sq2 - 2*dot, same formula as reference.
#pragma unroll 2
    for (int n = 0; n < NCHUNK; ++n) {
        float4 t = sT[n];
#pragma unroll
        for (int i = 0; i < TM; ++i) {
            float c = x1[i] * t.x;
            c = fmaf(y1[i], t.y, c);
            c = fmaf(z1[i], t.z, c);
            float d2 = fmaf(-2.0f, c, sq1[i] + t.w);
            bool lt = d2 < best[i];          // strict: keeps earliest n on tie
            bi[i]   = lt ? n : bi[i];
            best[i] = lt ? d2 : best[i];
        }
    }

#pragma unroll
    for (int i = 0; i < TM; ++i) {
        int m = mBase + (int)threadIdx.x + i * BLK;
        float b2 = fmaxf(best[i], 1e-12f);   // matches reference EPS clamp
        // d2 >= EPS > 0 -> float bit pattern preserves order as uint.
        // Low 32 bits = global n: ties across chunks resolve to smallest n,
        // exactly matching argmin's first-occurrence semantics.
        unsigned long long key =
            ((unsigned long long)__float_as_uint(b2) << 32) |
            (unsigned long long)(unsigned int)(n0 + bi[i]);
        atomicMin(&keys[(size_t)b * Mq + m], key);
    }
}

__global__ __launch_bounds__(BLK) void combine_kernel(
    const unsigned long long* __restrict__ keys,
    const float* __restrict__ sigQ, const float* __restrict__ sigT,
    float* __restrict__ out, float scale, int Mq, int Nt)
{
    int gid = blockIdx.x * BLK + (int)threadIdx.x;   // over B*Mq
    unsigned long long key = keys[gid];
    float d2  = __uint_as_float((unsigned int)(key >> 32));
    int   idx = (int)(key & 0xFFFFFFFFu);
    int   b   = gid / Mq;

    float s = 0.5f * (sigQ[gid] + sigT[(size_t)b * Nt + idx]);
    float v = (logf(s) + sqrtf(d2) / s) * scale;

    __shared__ float red[BLK];
    red[threadIdx.x] = v;
    __syncthreads();
    for (int st = BLK / 2; st > 0; st >>= 1) {
        if ((int)threadIdx.x < st) red[threadIdx.x] += red[threadIdx.x + st];
        __syncthreads();
    }
    if (threadIdx.x == 0) atomicAdd(out, red[0]);
}

extern "C" void kernel_launch(void* const* d_in, const int* in_sizes, int n_in,
                              void* d_out, int out_size, void* d_ws, size_t ws_size,
                              hipStream_t stream) {
    const float* k1 = (const float*)d_in[0];   // (B,3,M)
    const float* k2 = (const float*)d_in[1];   // (B,3,N)
    const float* s1 = (const float*)d_in[2];   // (B,M)
    const float* s2 = (const float*)d_in[3];   // (B,N)
    float* out = (float*)d_out;

    const int B = 16, M = 4096, N = 4096;

    unsigned long long* keysF = (unsigned long long*)d_ws;           // B*M keys
    unsigned long long* keysB = keysF + (size_t)B * M;               // B*N keys

    // Init keys to u64-max; zero the output accumulator (d_out is poisoned,
    // never re-poisoned between replays -> must rewrite every launch).
    hipMemsetAsync(d_ws, 0xFF, (size_t)B * (M + N) * sizeof(unsigned long long), stream);
    hipMemsetAsync(d_out, 0, sizeof(float), stream);

    nn_kernel<<<B * (M / MTILE) * (N / NCHUNK), BLK, 0, stream>>>(k1, k2, keysF, M, N);
    nn_kernel<<<B * (N / MTILE) * (M / NCHUNK), BLK, 0, stream>>>(k2, k1, keysB, N, M);

    combine_kernel<<<(B * M) / BLK, BLK, 0, stream>>>(keysF, s1, s2, out,
                                                      1.0f / (float)(B * M), M, N);
    combine_kernel<<<(B * N) / BLK, BLK, 0, stream>>>(keysB, s2, s1, out,
                                                      1.0f / (float)(B * N), N, M);
}

// Round 2
// 99.841 us; speedup vs baseline: 1.3375x; 1.3375x over previous
//
#include <hip/hip_runtime.h>
#include <cstdint>

// ChamferLoss on MI355X.
//   nn_kernel (x2, roles swapped): per query point, min over targets of
//     e = ||t||^2 - 2 q.t  (== d2 minus per-query const ||q||^2, same argmin).
//     Targets staged in LDS premultiplied: (-2x,-2y,-2z, ||t||^2) -> inner
//     loop is 3 fma + cmp + 2 cndmask = 6 VALU/pair.
//     Chunk partials merged via atomicMin on u64 (monotone(e)<<32 | n).
//   combine_kernel (x2): decode e, re-add ||q||^2, EPS clamp (commutes with
//     min), sqrt, gather partner sigma, log+div, block-reduce, atomicAdd.

#define BLK 256
#define TM 4
#define MTILE (BLK * TM)   // 1024 query points per block
#define NCHUNK 256         // target points staged in LDS per block

// Monotone float -> uint transform (preserves total order incl. negatives).
__device__ __forceinline__ unsigned int f2mono(float f) {
    unsigned int u = __float_as_uint(f);
    return (u & 0x80000000u) ? ~u : (u | 0x80000000u);
}
__device__ __forceinline__ float mono2f(unsigned int u) {
    return __uint_as_float((u & 0x80000000u) ? (u ^ 0x80000000u) : ~u);
}

__global__ __launch_bounds__(BLK) void nn_kernel(
    const float* __restrict__ Q, const float* __restrict__ T,
    unsigned long long* __restrict__ keys, int Mq, int Nt)
{
    const int nChunks = Nt / NCHUNK;
    const int mTiles  = Mq / MTILE;
    int bid = blockIdx.x;
    int nc = bid % nChunks;
    int mt = (bid / nChunks) % mTiles;
    int b  = bid / (nChunks * mTiles);

    __shared__ float4 sT[NCHUNK];

    const float* Tb = T + (size_t)b * 3 * Nt;
    const int n0 = nc * NCHUNK;
    // Stage premultiplied target chunk: (-2x, -2y, -2z, x^2+y^2+z^2).
    for (int i = threadIdx.x; i < NCHUNK; i += BLK) {
        float x = Tb[0 * Nt + n0 + i];
        float y = Tb[1 * Nt + n0 + i];
        float z = Tb[2 * Nt + n0 + i];
        sT[i] = make_float4(-2.0f * x, -2.0f * y, -2.0f * z,
                            fmaf(x, x, fmaf(y, y, z * z)));
    }
    __syncthreads();

    const float* Qb = Q + (size_t)b * 3 * Mq;
    const int mBase = mt * MTILE;

    float x1[TM], y1[TM], z1[TM], best[TM];
    int bi[TM];
#pragma unroll
    for (int i = 0; i < TM; ++i) {
        int m = mBase + (int)threadIdx.x + i * BLK;   // coalesced
        x1[i] = Qb[0 * Mq + m];
        y1[i] = Qb[1 * Mq + m];
        z1[i] = Qb[2 * Mq + m];
        best[i] = 3.402823466e38f;
        bi[i] = 0;
    }

    // 3 fma + cmp + 2 cndmask per pair; LDS float4 broadcast read per n.
#pragma unroll 4
    for (int n = 0; n < NCHUNK; ++n) {
        float4 t = sT[n];
#pragma unroll
        for (int i = 0; i < TM; ++i) {
            float e = fmaf(t.x, x1[i], fmaf(t.y, y1[i], fmaf(t.z, z1[i], t.w)));
            bool lt = e < best[i];           // strict: keeps earliest n on tie
            bi[i]   = lt ? n : bi[i];
            best[i] = lt ? e : best[i];
        }
    }

#pragma unroll
    for (int i = 0; i < TM; ++i) {
        int m = mBase + (int)threadIdx.x + i * BLK;
        // Monotone transform handles negative e; low 32 bits = global n so
        // ties across chunks resolve to smallest n (argmin first-occurrence).
        unsigned long long key =
            ((unsigned long long)f2mono(best[i]) << 32) |
            (unsigned long long)(unsigned int)(n0 + bi[i]);
        atomicMin(&keys[(size_t)b * Mq + m], key);
    }
}

__global__ __launch_bounds__(BLK) void combine_kernel(
    const unsigned long long* __restrict__ keys,
    const float* __restrict__ Q,
    const float* __restrict__ sigQ, const float* __restrict__ sigT,
    float* __restrict__ out, float scale, int Mq, int Nt)
{
    int gid = blockIdx.x * BLK + (int)threadIdx.x;   // over B*Mq
    unsigned long long key = keys[gid];
    float e   = mono2f((unsigned int)(key >> 32));
    int   idx = (int)(key & 0xFFFFFFFFu);
    int   b   = gid / Mq;
    int   m   = gid - b * Mq;

    const float* Qb = Q + (size_t)b * 3 * Mq;
    float x = Qb[0 * Mq + m], y = Qb[1 * Mq + m], z = Qb[2 * Mq + m];
    float sq1 = fmaf(x, x, fmaf(y, y, z * z));
    float d2 = fmaxf(sq1 + e, 1e-12f);               // reference EPS clamp

    float s = 0.5f * (sigQ[gid] + sigT[(size_t)b * Nt + idx]);
    float v = (logf(s) + sqrtf(d2) / s) * scale;

    __shared__ float red[BLK];
    red[threadIdx.x] = v;
    __syncthreads();
    for (int st = BLK / 2; st > 0; st >>= 1) {
        if ((int)threadIdx.x < st) red[threadIdx.x] += red[threadIdx.x + st];
        __syncthreads();
    }
    if (threadIdx.x == 0) atomicAdd(out, red[0]);
}

extern "C" void kernel_launch(void* const* d_in, const int* in_sizes, int n_in,
                              void* d_out, int out_size, void* d_ws, size_t ws_size,
                              hipStream_t stream) {
    const float* k1 = (const float*)d_in[0];   // (B,3,M)
    const float* k2 = (const float*)d_in[1];   // (B,3,N)
    const float* s1 = (const float*)d_in[2];   // (B,M)
    const float* s2 = (const float*)d_in[3];   // (B,N)
    float* out = (float*)d_out;

    const int B = 16, M = 4096, N = 4096;

    unsigned long long* keysF = (unsigned long long*)d_ws;           // B*M keys
    unsigned long long* keysB = keysF + (size_t)B * M;               // B*N keys

    hipMemsetAsync(d_ws, 0xFF, (size_t)B * (M + N) * sizeof(unsigned long long), stream);
    hipMemsetAsync(d_out, 0, sizeof(float), stream);

    nn_kernel<<<B * (M / MTILE) * (N / NCHUNK), BLK, 0, stream>>>(k1, k2, keysF, M, N);
    nn_kernel<<<B * (N / MTILE) * (M / NCHUNK), BLK, 0, stream>>>(k2, k1, keysB, N, M);

    combine_kernel<<<(B * M) / BLK, BLK, 0, stream>>>(keysF, k1, s1, s2, out,
                                                      1.0f / (float)(B * M), M, N);
    combine_kernel<<<(B * N) / BLK, BLK, 0, stream>>>(keysB, k2, s2, s1, out,
                                                      1.0f / (float)(B * N), N, M);
}

// Round 3
// 68.411 us; speedup vs baseline: 1.9519x; 1.4594x over previous
//
#include <hip/hip_runtime.h>
#include <cstdint>

// ChamferLoss on MI355X.
//   nn_kernel (x2, roles swapped): per query point, group-hierarchical min of
//     e = ||t||^2 - 2 q.t over targets (same argmin as d2; ||q||^2 re-added
//     later). Queries premultiplied by -2 in registers -> inner loop is
//     3 fma + ~0.5 min (v_min3 fusion) per pair; (best, group) update once
//     per 16 pairs. Chunk partials merged via atomicMin on u64
//     (monotone(e)<<32 | global_group_id).
//   combine_kernel (x2): recompute the 16 distances of the winning group
//     BIT-IDENTICALLY (same fmaf chains), strict-< scan for first-occurrence
//     argmin, EPS clamp, sqrt, gather partner sigma, log+div, block-reduce,
//     atomicAdd into d_out (memset to 0 each launch).

#define BLK 256
#define TM 4
#define MTILE (BLK * TM)   // 1024 query points per block
#define NCHUNK 256         // target points staged in LDS per block
#define G 16               // argmin group size

// Monotone float -> uint transform (preserves total order incl. negatives).
__device__ __forceinline__ unsigned int f2mono(float f) {
    unsigned int u = __float_as_uint(f);
    return (u & 0x80000000u) ? ~u : (u | 0x80000000u);
}

__global__ __launch_bounds__(BLK) void nn_kernel(
    const float* __restrict__ Q, const float* __restrict__ T,
    unsigned long long* __restrict__ keys, int Mq, int Nt)
{
    const int nChunks = Nt / NCHUNK;
    const int mTiles  = Mq / MTILE;
    int bid = blockIdx.x;
    int nc = bid % nChunks;
    int mt = (bid / nChunks) % mTiles;
    int b  = bid / (nChunks * mTiles);

    __shared__ float4 sT[NCHUNK];

    const float* Tb = T + (size_t)b * 3 * Nt;
    const int n0 = nc * NCHUNK;
    {   // BLK == NCHUNK: one float4 per thread. w-formula must match combine.
        int i = threadIdx.x;
        float x = Tb[0 * Nt + n0 + i];
        float y = Tb[1 * Nt + n0 + i];
        float z = Tb[2 * Nt + n0 + i];
        sT[i] = make_float4(x, y, z, fmaf(x, x, fmaf(y, y, z * z)));
    }
    __syncthreads();

    const float* Qb = Q + (size_t)b * 3 * Mq;
    const int mBase = mt * MTILE;

    float qx[TM], qy[TM], qz[TM], best[TM];
    int bg[TM];
#pragma unroll
    for (int i = 0; i < TM; ++i) {
        int m = mBase + (int)threadIdx.x + i * BLK;   // coalesced
        qx[i] = -2.0f * Qb[0 * Mq + m];               // exact scaling
        qy[i] = -2.0f * Qb[1 * Mq + m];
        qz[i] = -2.0f * Qb[2 * Mq + m];
        best[i] = 3.402823466e38f;
        bg[i] = 0;
    }

    for (int g = 0; g < NCHUNK / G; ++g) {
        float gmin[TM];
#pragma unroll
        for (int i = 0; i < TM; ++i) gmin[i] = 3.402823466e38f;
#pragma unroll
        for (int k = 0; k < G; k += 2) {
            float4 ta = sT[g * G + k];
            float4 tb = sT[g * G + k + 1];
#pragma unroll
            for (int i = 0; i < TM; ++i) {
                float e0 = fmaf(ta.x, qx[i], fmaf(ta.y, qy[i], fmaf(ta.z, qz[i], ta.w)));
                float e1 = fmaf(tb.x, qx[i], fmaf(tb.y, qy[i], fmaf(tb.z, qz[i], tb.w)));
                gmin[i] = fminf(gmin[i], fminf(e0, e1));   // -> v_min3_f32
            }
        }
#pragma unroll
        for (int i = 0; i < TM; ++i) {
            bool lt = gmin[i] < best[i];   // strict: keeps earliest group on tie
            bg[i]   = lt ? g : bg[i];
            best[i] = lt ? gmin[i] : best[i];
        }
    }

#pragma unroll
    for (int i = 0; i < TM; ++i) {
        int m = mBase + (int)threadIdx.x + i * BLK;
        // High bits: order-preserving transform of e (can be negative).
        // Low bits: GLOBAL group id -> value ties resolve to earliest group.
        unsigned long long key =
            ((unsigned long long)f2mono(best[i]) << 32) |
            (unsigned long long)(unsigned int)(n0 / G + bg[i]);
        atomicMin(&keys[(size_t)b * Mq + m], key);
    }
}

__global__ __launch_bounds__(BLK) void combine_kernel(
    const unsigned long long* __restrict__ keys,
    const float* __restrict__ Q, const float* __restrict__ T,
    const float* __restrict__ sigQ, const float* __restrict__ sigT,
    float* __restrict__ out, float scale, int Mq, int Nt)
{
    int gid = blockIdx.x * BLK + (int)threadIdx.x;   // over B*Mq
    unsigned long long key = keys[gid];
    int group = (int)(key & 0xFFFFFFFFu);
    int b = gid / Mq;
    int m = gid - b * Mq;

    const float* Qb = Q + (size_t)b * 3 * Mq;
    const float* Tb = T + (size_t)b * 3 * Nt;
    float x = Qb[0 * Mq + m], y = Qb[1 * Mq + m], z = Qb[2 * Mq + m];
    float qx = -2.0f * x, qy = -2.0f * y, qz = -2.0f * z;
    float sq1 = fmaf(x, x, fmaf(y, y, z * z));

    // Recompute the winning group's 16 e-values with the IDENTICAL fmaf
    // chains used in nn_kernel -> bit-identical; strict < scan gives the
    // first-occurrence argmin within the winning (earliest) group.
    int nbase = group * G;
    float beste = 3.402823466e38f;
    int bi = nbase;
#pragma unroll
    for (int k = 0; k < G; ++k) {
        int n = nbase + k;
        float tx = Tb[0 * Nt + n], ty = Tb[1 * Nt + n], tz = Tb[2 * Nt + n];
        float w = fmaf(tx, tx, fmaf(ty, ty, tz * tz));
        float e = fmaf(tx, qx, fmaf(ty, qy, fmaf(tz, qz, w)));
        bool lt = e < beste;
        bi    = lt ? n : bi;
        beste = lt ? e : beste;
    }

    float d2 = fmaxf(sq1 + beste, 1e-12f);           // reference EPS clamp
    float s = 0.5f * (sigQ[gid] + sigT[(size_t)b * Nt + bi]);
    float v = (logf(s) + sqrtf(d2) / s) * scale;

    __shared__ float red[BLK];
    red[threadIdx.x] = v;
    __syncthreads();
    for (int st = BLK / 2; st > 0; st >>= 1) {
        if ((int)threadIdx.x < st) red[threadIdx.x] += red[threadIdx.x + st];
        __syncthreads();
    }
    if (threadIdx.x == 0) atomicAdd(out, red[0]);
}

extern "C" void kernel_launch(void* const* d_in, const int* in_sizes, int n_in,
                              void* d_out, int out_size, void* d_ws, size_t ws_size,
                              hipStream_t stream) {
    const float* k1 = (const float*)d_in[0];   // (B,3,M)
    const float* k2 = (const float*)d_in[1];   // (B,3,N)
    const float* s1 = (const float*)d_in[2];   // (B,M)
    const float* s2 = (const float*)d_in[3];   // (B,N)
    float* out = (float*)d_out;

    const int B = 16, M = 4096, N = 4096;

    unsigned long long* keysF = (unsigned long long*)d_ws;           // B*M keys
    unsigned long long* keysB = keysF + (size_t)B * M;               // B*N keys

    hipMemsetAsync(d_ws, 0xFF, (size_t)B * (M + N) * sizeof(unsigned long long), stream);
    hipMemsetAsync(d_out, 0, sizeof(float), stream);

    nn_kernel<<<B * (M / MTILE) * (N / NCHUNK), BLK, 0, stream>>>(k1, k2, keysF, M, N);
    nn_kernel<<<B * (N / MTILE) * (M / NCHUNK), BLK, 0, stream>>>(k2, k1, keysB, N, M);

    combine_kernel<<<(B * M) / BLK, BLK, 0, stream>>>(keysF, k1, k2, s1, s2, out,
                                                      1.0f / (float)(B * M), M, N);
    combine_kernel<<<(B * N) / BLK, BLK, 0, stream>>>(keysB, k2, k1, s2, s1, out,
                                                      1.0f / (float)(B * N), N, M);
}

// Round 4
// 61.083 us; speedup vs baseline: 2.1861x; 1.1200x over previous
//
#include <hip/hip_runtime.h>
#include <cstdint>

// ChamferLoss on MI355X.
//   nn_kernel (x2, roles swapped): per query, group-hierarchical min of
//     e = ||t||^2 - 2 q.t. x,y products via v_dot2_f32_f16 (f16 inputs, f32
//     accumulate); z product and ||t||^2 kept exact fp32:
//       e = fdot2(t_xy_h2, q_xy_h2, fmaf(t_z, -2*q_z, ||t||^2))
//     -> 2 VALU/pair + ~0.7 fold/bookkeeping. Targets staged SoA in LDS,
//     read 4-at-a-time (3x ds_read_b128 per 4 targets). Chunk partials merge
//     via atomicMin on u64 (monotone(e)<<32 | global_group_id).
//   combine_kernel (x2): recompute winning group's 16 e-values with the
//     BIT-IDENTICAL f16 path -> first-occurrence in-group argmin; then exact
//     fp32 d2 for the selected index, EPS clamp, sqrt, sigma gather, log+div,
//     block-reduce to per-block partials (no global atomics).
//   final_reduce: sums 512 partials -> d_out.

#define BLK 256
#define TM 2
#define MTILE (BLK * TM)   // 512 query points per block
#define NCHUNK 256         // target points staged in LDS per block
#define G 16               // argmin group size
#define FLT_BIG 3.402823466e38f

typedef _Float16 h2 __attribute__((ext_vector_type(2)));

// Monotone float -> uint transform (preserves total order incl. negatives).
__device__ __forceinline__ unsigned int f2mono(float f) {
    unsigned int u = __float_as_uint(f);
    return (u & 0x80000000u) ? ~u : (u | 0x80000000u);
}

__device__ __forceinline__ unsigned int packh2(float a, float b) {
    h2 v = { (_Float16)a, (_Float16)b };
    return __builtin_bit_cast(unsigned int, v);
}

// Must be used identically in nn_kernel and combine_kernel (bit-identical path).
__device__ __forceinline__ float edot(unsigned int txy_bits, h2 qxy, float acc) {
#if __has_builtin(__builtin_amdgcn_fdot2)
    return __builtin_amdgcn_fdot2(__builtin_bit_cast(h2, txy_bits), qxy, acc, false);
#else
    h2 t = __builtin_bit_cast(h2, txy_bits);
    return fmaf((float)t.x, (float)qxy.x, fmaf((float)t.y, (float)qxy.y, acc));
#endif
}

__global__ __launch_bounds__(BLK) void nn_kernel(
    const float* __restrict__ Q, const float* __restrict__ T,
    unsigned long long* __restrict__ keys, int Mq, int Nt)
{
    const int nChunks = Nt / NCHUNK;
    const int mTiles  = Mq / MTILE;
    int bid = blockIdx.x;
    int nc = bid % nChunks;
    int mt = (bid / nChunks) % mTiles;
    int b  = bid / (nChunks * mTiles);

    __shared__ __align__(16) unsigned int sXY[NCHUNK];
    __shared__ __align__(16) float        sZ[NCHUNK];
    __shared__ __align__(16) float        sW[NCHUNK];

    const float* Tb = T + (size_t)b * 3 * Nt;
    const int n0 = nc * NCHUNK;
    {   // BLK == NCHUNK: one target per thread. w-formula must match combine.
        int i = threadIdx.x;
        float x = Tb[0 * Nt + n0 + i];
        float y = Tb[1 * Nt + n0 + i];
        float z = Tb[2 * Nt + n0 + i];
        sXY[i] = packh2(x, y);
        sZ[i]  = z;
        sW[i]  = fmaf(x, x, fmaf(y, y, z * z));
    }
    __syncthreads();

    const float* Qb = Q + (size_t)b * 3 * Mq;
    const int mBase = mt * MTILE;

    h2 qxy[TM];
    float qz[TM], best[TM];
    int bg[TM];
#pragma unroll
    for (int i = 0; i < TM; ++i) {
        int m = mBase + (int)threadIdx.x + i * BLK;   // coalesced
        float x = Qb[0 * Mq + m];
        float y = Qb[1 * Mq + m];
        float z = Qb[2 * Mq + m];
        qxy[i] = { (_Float16)(-2.0f * x), (_Float16)(-2.0f * y) };
        qz[i]  = -2.0f * z;
        best[i] = FLT_BIG;
        bg[i] = 0;
    }

    const uint4*  sXY4 = (const uint4*)sXY;
    const float4* sZ4  = (const float4*)sZ;
    const float4* sW4  = (const float4*)sW;

    for (int g = 0; g < NCHUNK / G; ++g) {
        float gmin[TM];
#pragma unroll
        for (int i = 0; i < TM; ++i) gmin[i] = FLT_BIG;
#pragma unroll
        for (int s4 = 0; s4 < G / 4; ++s4) {
            int idx = g * (G / 4) + s4;
            uint4  xy = sXY4[idx];
            float4 zz = sZ4[idx];
            float4 ww = sW4[idx];
#pragma unroll
            for (int i = 0; i < TM; ++i) {
                float ea = edot(xy.x, qxy[i], fmaf(zz.x, qz[i], ww.x));
                float eb = edot(xy.y, qxy[i], fmaf(zz.y, qz[i], ww.y));
                float ec = edot(xy.z, qxy[i], fmaf(zz.z, qz[i], ww.z));
                float ed = edot(xy.w, qxy[i], fmaf(zz.w, qz[i], ww.w));
                // 2x v_min3_f32
                gmin[i] = fminf(fminf(ea, eb), fminf(fminf(ec, ed), gmin[i]));
            }
        }
#pragma unroll
        for (int i = 0; i < TM; ++i) {
            bool lt = gmin[i] < best[i];   // strict: keeps earliest group on tie
            bg[i]   = lt ? g : bg[i];
            best[i] = lt ? gmin[i] : best[i];
        }
    }

#pragma unroll
    for (int i = 0; i < TM; ++i) {
        int m = mBase + (int)threadIdx.x + i * BLK;
        unsigned long long key =
            ((unsigned long long)f2mono(best[i]) << 32) |
            (unsigned long long)(unsigned int)(n0 / G + bg[i]);
        atomicMin(&keys[(size_t)b * Mq + m], key);
    }
}

__global__ __launch_bounds__(BLK) void combine_kernel(
    const unsigned long long* __restrict__ keys,
    const float* __restrict__ Q, const float* __restrict__ T,
    const float* __restrict__ sigQ, const float* __restrict__ sigT,
    float* __restrict__ partials, float scale, int Mq, int Nt)
{
    int gid = blockIdx.x * BLK + (int)threadIdx.x;   // over B*Mq
    unsigned long long key = keys[gid];
    int group = (int)(key & 0xFFFFFFFFu);
    int b = gid / Mq;
    int m = gid - b * Mq;

    const float* Qb = Q + (size_t)b * 3 * Mq;
    const float* Tb = T + (size_t)b * 3 * Nt;
    float x = Qb[0 * Mq + m], y = Qb[1 * Mq + m], z = Qb[2 * Mq + m];
    h2 qxy = { (_Float16)(-2.0f * x), (_Float16)(-2.0f * y) };
    float qz = -2.0f * z;
    float sq1 = fmaf(x, x, fmaf(y, y, z * z));

    // Scan winning group with the IDENTICAL f16 e-path used in nn_kernel ->
    // bit-identical values; strict < gives first-occurrence in-group argmin.
    int nbase = group * G;
    float beste = FLT_BIG;
    int bi = nbase;
#pragma unroll
    for (int k = 0; k < G; ++k) {
        int n = nbase + k;
        float tx = Tb[0 * Nt + n], ty = Tb[1 * Nt + n], tz = Tb[2 * Nt + n];
        float w = fmaf(tx, tx, fmaf(ty, ty, tz * tz));
        float e = edot(packh2(tx, ty), qxy, fmaf(tz, qz, w));
        bool lt = e < beste;
        bi    = lt ? n : bi;
        beste = lt ? e : beste;
    }

    // Exact fp32 distance of the selected index (loss uses true d, so f16
    // selection noise only contributes via near-tie argmin flips).
    float tx = Tb[0 * Nt + bi], ty = Tb[1 * Nt + bi], tz = Tb[2 * Nt + bi];
    float w  = fmaf(tx, tx, fmaf(ty, ty, tz * tz));
    float cross = fmaf(x, tx, fmaf(y, ty, z * tz));
    float d2 = fmaxf(fmaf(-2.0f, cross, sq1 + w), 1e-12f);   // reference EPS

    float s = 0.5f * (sigQ[gid] + sigT[(size_t)b * Nt + bi]);
    float v = (logf(s) + sqrtf(d2) / s) * scale;

    __shared__ float red[BLK];
    red[threadIdx.x] = v;
    __syncthreads();
    for (int st = BLK / 2; st > 0; st >>= 1) {
        if ((int)threadIdx.x < st) red[threadIdx.x] += red[threadIdx.x + st];
        __syncthreads();
    }
    if (threadIdx.x == 0) partials[blockIdx.x] = red[0];
}

__global__ __launch_bounds__(512) void final_reduce(
    const float* __restrict__ partials, float* __restrict__ out, int n)
{
    __shared__ float red[512];
    int t = threadIdx.x;
    red[t] = (t < n) ? partials[t] : 0.0f;
    __syncthreads();
    for (int st = 256; st > 0; st >>= 1) {
        if (t < st) red[t] += red[t + st];
        __syncthreads();
    }
    if (t == 0) out[0] = red[0];
}

extern "C" void kernel_launch(void* const* d_in, const int* in_sizes, int n_in,
                              void* d_out, int out_size, void* d_ws, size_t ws_size,
                              hipStream_t stream) {
    const float* k1 = (const float*)d_in[0];   // (B,3,M)
    const float* k2 = (const float*)d_in[1];   // (B,3,N)
    const float* s1 = (const float*)d_in[2];   // (B,M)
    const float* s2 = (const float*)d_in[3];   // (B,N)
    float* out = (float*)d_out;

    const int B = 16, M = 4096, N = 4096;

    unsigned long long* keysF = (unsigned long long*)d_ws;           // B*M keys
    unsigned long long* keysB = keysF + (size_t)B * M;               // B*N keys
    float* partials = (float*)(keysB + (size_t)B * N);               // 512 floats
    const int PF = (B * M) / BLK;                                    // 256
    const int PB = (B * N) / BLK;                                    // 256

    hipMemsetAsync(d_ws, 0xFF, (size_t)B * (M + N) * sizeof(unsigned long long), stream);

    nn_kernel<<<B * (M / MTILE) * (N / NCHUNK), BLK, 0, stream>>>(k1, k2, keysF, M, N);
    nn_kernel<<<B * (N / MTILE) * (M / NCHUNK), BLK, 0, stream>>>(k2, k1, keysB, N, M);

    combine_kernel<<<PF, BLK, 0, stream>>>(keysF, k1, k2, s1, s2, partials,
                                           1.0f / (float)(B * M), M, N);
    combine_kernel<<<PB, BLK, 0, stream>>>(keysB, k2, k1, s2, s1, partials + PF,
                                           1.0f / (float)(B * N), N, M);

    final_reduce<<<1, 512, 0, stream>>>(partials, out, PF + PB);
}